// Round 10
// baseline (396.292 us; speedup 1.0000x reference)
//
#include <hip/hip_runtime.h>
#include <hip/hip_bf16.h>

typedef __attribute__((ext_vector_type(8))) short bf16x8;
typedef __attribute__((ext_vector_type(4))) short bf16x4;
typedef __attribute__((ext_vector_type(4))) float f32x4;

__device__ __forceinline__ short f2bf(float f){
  __hip_bfloat16 h = __float2bfloat16(f);
  return __builtin_bit_cast(short, h);
}
__device__ __forceinline__ float bf2f(short s){
  unsigned u = ((unsigned)(unsigned short)s) << 16;
  return __builtin_bit_cast(float, u);
}

__device__ __forceinline__ void gload_lds16(const short* g, char* l){
  __builtin_amdgcn_global_load_lds(
      (const __attribute__((address_space(1))) void*)g,
      (__attribute__((address_space(3))) void*)l, 16, 0, 0);
}

#define SB0() __builtin_amdgcn_sched_barrier(0)

// ---------------- GroupNorm stats ----------------
__global__ __launch_bounds__(256) void gn_stats(const float* __restrict__ x,
                                                float* __restrict__ stats){
  int b = blockIdx.x >> 5, g = blockIdx.x & 31;
  const float4* p = (const float4*)(x + ((long long)b*512 + g*16)*4096);
  float s = 0.f, s2 = 0.f;
  for (int i = threadIdx.x; i < 16384; i += 256){
    float4 v = p[i];
    s  += v.x + v.y + v.z + v.w;
    s2 += v.x*v.x + v.y*v.y + v.z*v.z + v.w*v.w;
  }
  #pragma unroll
  for (int o = 32; o; o >>= 1){ s += __shfl_xor(s, o); s2 += __shfl_xor(s2, o); }
  __shared__ float rs[4], rs2[4];
  int wid = threadIdx.x >> 6;
  if ((threadIdx.x & 63) == 0){ rs[wid] = s; rs2[wid] = s2; }
  __syncthreads();
  if (threadIdx.x == 0){
    float S  = rs[0]+rs[1]+rs[2]+rs[3];
    float S2 = rs2[0]+rs2[1]+rs2[2]+rs2[3];
    float mean = S * (1.f/65536.f);
    float var  = S2 * (1.f/65536.f) - mean*mean;
    stats[blockIdx.x*2]   = mean;
    stats[blockIdx.x*2+1] = rsqrtf(var + 1e-6f);
  }
}

// ------------- GN apply + transpose -> h bf16 [B,N,C] ------------------
__global__ __launch_bounds__(256) void gn_apply(const float* __restrict__ x,
                                                const float* __restrict__ stats,
                                                const float* __restrict__ gw,
                                                const float* __restrict__ gb,
                                                short* __restrict__ h){
  __shared__ float tile[128][65];
  int b  = blockIdx.y;
  int n0 = blockIdx.x * 64;
  int t  = threadIdx.x;
  const float* xb = x + (long long)b*512*4096;
  for (int cc = 0; cc < 4; cc++){
    int c0 = cc*128;
    #pragma unroll
    for (int r = 0; r < 128; r += 4){
      int c = r + (t >> 6);
      tile[c][t & 63] = xb[(long long)(c0+c)*4096 + n0 + (t & 63)];
    }
    __syncthreads();
    int n = t >> 2, cp = (t & 3)*32;
    short tmp[32];
    #pragma unroll
    for (int j = 0; j < 32; j++){
      int c = c0 + cp + j;
      float mean = stats[(b*32 + (c >> 4))*2];
      float rstd = stats[(b*32 + (c >> 4))*2 + 1];
      float v = (tile[cp+j][n] - mean)*rstd*gw[c] + gb[c];
      tmp[j] = f2bf(v);
    }
    long long ho = ((long long)b*4096 + n0 + n)*512 + c0 + cp;
    #pragma unroll
    for (int j2 = 0; j2 < 4; j2++){
      bf16x8 v8;
      #pragma unroll
      for (int e = 0; e < 8; e++) v8[e] = tmp[j2*8 + e];
      *(bf16x8*)&h[ho + j2*8] = v8;
    }
    __syncthreads();
  }
}

// ---------- fp32 -> bf16 weights ----------
__global__ __launch_bounds__(256) void f2bf_all(
    const float* __restrict__ w0, const float* __restrict__ w1,
    const float* __restrict__ w2, const float* __restrict__ w3,
    short* __restrict__ o0, short* __restrict__ o1,
    short* __restrict__ o2, short* __restrict__ o3){
  int idx = blockIdx.x*256 + threadIdx.x;
  int m = idx >> 15, r = idx & 32767;
  const float* src = (m==0) ? w0 : (m==1) ? w1 : (m==2) ? w2 : w3;
  short* dst       = (m==0) ? o0 : (m==1) ? o1 : (m==2) ? o2 : o3;
  const float4* p = (const float4*)src + (long long)r*2;
  float4 a = p[0], c = p[1];
  bf16x8 v;
  v[0]=f2bf(a.x); v[1]=f2bf(a.y); v[2]=f2bf(a.z); v[3]=f2bf(a.w);
  v[4]=f2bf(c.x); v[5]=f2bf(c.y); v[6]=f2bf(c.z); v[7]=f2bf(c.w);
  *(bf16x8*)&dst[(long long)r*8] = v;
}

// ---------------- denominator reduce ----------------
__global__ __launch_bounds__(256) void reduce_den(const float* __restrict__ partial,
                                                  float* __restrict__ inv_den,
                                                  int nrows){
  int r = blockIdx.x*256 + threadIdx.x;
  if (r >= nrows) return;
  const float4* p = (const float4*)(partial + (long long)r*16);
  float4 a = p[0], b = p[1], c = p[2], d = p[3];
  float s = a.x+a.y+a.z+a.w + b.x+b.y+b.z+b.w + c.x+c.y+c.z+c.w + d.x+d.y+d.z+d.w;
  inv_den[r] = 1.f / s;
}

// ======= 256xBN bf16 GEMM, 4 waves, wave-tile 128x(BN/2), BK=32 ==============
// Big wave-tile: per wave per K-tile only 16 (or 12) ds_read_b128 feed 64 (or
// 32) independent MFMA chains -> MFMA-bound issue ratio + deep intra-wave ILP.
// acc lives in the unified VGPR/AGPR file (~350 regs, 1 wave/SIMD).
// Staging+swizzle verbatim from the r6-verified [rows][32] layout (0 bank
// conflicts); dbuf + counted vmcnt skeleton from r9 (race-correct).
// MODE 0: bf16 [M][Nn] + bias + scale (swapped operands, direct stores)
// MODE 1: bf16 [Nn][M] transposed + bias
// MODE 2: fp32 [Nn][M] + bias + residual
// MODE 4: scores: p' = exp(acc) bf16 + per-(row,by) partial sums
// MODE 5: PV: bf16 [M][Nn], acc * inv_den[row]
template<int MODE, int BN, int SWZ>
__global__ __launch_bounds__(256, 1) void gemmW(
    const short* __restrict__ A, const short* __restrict__ Bw,
    const float* __restrict__ bias,
    void* __restrict__ outp, const float* __restrict__ resid,
    int M, int Nn, int Kd,
    long long sA, long long sB, long long sO, float scale,
    const float* __restrict__ dptr, float* __restrict__ partial)
{
  constexpr int WN = BN/2;                // 128 or 64
  constexpr int MF = 8;                   // wave rows 128 = 8 frags
  constexpr int NF = WN/16;               // 8 or 4
  constexpr int ABYT = 16384;             // A: 256x32 bf16
  constexpr int BBYT = BN*64;             // B: BNx32 bf16
  constexpr int BUFSZ = ABYT + BBYT;
  constexpr int NBG = BN/64;              // B staging row-groups (4 or 2)
  extern __shared__ char smem[];

  int bx, by, bz;
  if constexpr (SWZ == 1){
    int id = blockIdx.x;
    int xcd = id & 7, s = id >> 3;
    int region = xcd + ((s >> 4) << 3);
    int o = s & 15;
    bz = region >> 4;
    bx = (region & 3)*4 + (o & 3);
    by = ((region >> 2) & 3)*4 + (o >> 2);
  } else if constexpr (SWZ == 2){
    int id = blockIdx.x;
    int xcd = id & 7, s = id >> 3;
    int combo = xcd*2 + (s & 1);
    by = combo & 3; bz = combo >> 2;
    bx = s >> 1;
  } else { bx = blockIdx.x; by = blockIdx.y; bz = blockIdx.z; }

  const short* Ab = A + bz*sA;
  const short* Bb = Bw + bz*sB;
  const int m0 = bx*256, n0 = by*BN;
  const int t = threadIdx.x;
  const int lane = t & 63, wid = t >> 6;
  const int g = lane >> 4, lr = lane & 15;
  const int wr = wid >> 1, wc = wid & 1;
  const long long KdLL = Kd;

  // staging (r6-verified): thread t covers (row group j)*64 + (t>>2), source
  // 16B-chunk (t&3)^((t>>3)&3); LDS dest linear j*4096 + t*16.
  const int srow = t >> 2;
  const int sch  = (t & 3) ^ ((t >> 3) & 3);
  const short* pA[4]; const short* pB[NBG];
  #pragma unroll
  for (int j = 0; j < 4; j++)
    pA[j] = Ab + (long long)(m0 + j*64 + srow)*KdLL + sch*8;
  #pragma unroll
  for (int j = 0; j < NBG; j++)
    pB[j] = Bb + (long long)(n0 + j*64 + srow)*KdLL + sch*8;
  const int t16 = t*16;

  // read offsets (r6-verified swizzle): row r chunk c at byte r*64 + ((c^((r>>1)&3))<<4)
  int offA[MF], offB[NF];
  #pragma unroll
  for (int mf = 0; mf < MF; mf++){
    int ra = wr*128 + mf*16 + lr;
    offA[mf] = ra*64 + ((g ^ ((ra >> 1) & 3)) << 4);
  }
  #pragma unroll
  for (int nf = 0; nf < NF; nf++){
    int rb = wc*WN + nf*16 + lr;
    offB[nf] = ABYT + rb*64 + ((g ^ ((rb >> 1) & 3)) << 4);
  }

  f32x4 acc[MF][NF];
  #pragma unroll
  for (int i = 0; i < MF; i++)
    #pragma unroll
    for (int j = 0; j < NF; j++)
      acc[i][j] = f32x4{0.f,0.f,0.f,0.f};

  auto STAGE = [&](int kt, int buf){
    char* d = smem + buf*BUFSZ;
    const long long ko = (long long)kt*32;
    #pragma unroll
    for (int j = 0; j < 4; j++)
      gload_lds16(pA[j] + ko, d + j*4096 + t16);
    #pragma unroll
    for (int j = 0; j < NBG; j++)
      gload_lds16(pB[j] + ko, d + ABYT + j*4096 + t16);
  };

  const int NT = Kd >> 5;   // BK=32

  STAGE(0, 0);
  STAGE(1, 1);
  if constexpr (NBG == 4) asm volatile("s_waitcnt vmcnt(8)":::"memory");
  else                    asm volatile("s_waitcnt vmcnt(6)":::"memory");
  SB0();
  __builtin_amdgcn_s_barrier();

  for (int kt = 0; kt < NT; ++kt){
    char* base = smem + (kt & 1)*BUFSZ;
    // one compiler-scheduled region: 12-16 ds_reads feed 32-64 indep. MFMAs
    bf16x8 av[MF], bv[NF];
    #pragma unroll
    for (int n = 0; n < NF; n++) bv[n] = *(const bf16x8*)(base + offB[n]);
    #pragma unroll
    for (int m = 0; m < MF; m++) av[m] = *(const bf16x8*)(base + offA[m]);
    #pragma unroll
    for (int m = 0; m < MF; m++)
      #pragma unroll
      for (int n = 0; n < NF; n++){
        if constexpr (MODE == 1 || MODE == 2)
          acc[m][n] = __builtin_amdgcn_mfma_f32_16x16x32_bf16(av[m], bv[n], acc[m][n], 0,0,0);
        else
          acc[m][n] = __builtin_amdgcn_mfma_f32_16x16x32_bf16(bv[n], av[m], acc[m][n], 0,0,0);
      }
    SB0();
    __builtin_amdgcn_s_barrier();
    SB0();                      // STAGE must not hoist above the barrier
    if (kt + 2 < NT){
      STAGE(kt + 2, kt & 1);
      if constexpr (NBG == 4) asm volatile("s_waitcnt vmcnt(8)":::"memory");
      else                    asm volatile("s_waitcnt vmcnt(6)":::"memory");
    } else {
      asm volatile("s_waitcnt vmcnt(0)":::"memory");
    }
    __builtin_amdgcn_s_barrier();
  }

  if constexpr (MODE == 0){
    short* outb = (short*)outp + bz*sO;
    const bool hb = (bias != nullptr);
    #pragma unroll
    for (int mi = 0; mi < MF; mi++){
      int row = m0 + wr*128 + mi*16 + lr;
      #pragma unroll
      for (int ni = 0; ni < NF; ni++){
        int col = n0 + wc*WN + ni*16 + g*4;
        float b0=0.f,b1=0.f,b2=0.f,b3=0.f;
        if (hb){ float4 bb = *(const float4*)&bias[col]; b0=bb.x; b1=bb.y; b2=bb.z; b3=bb.w; }
        bf16x4 pk;
        pk[0] = f2bf((acc[mi][ni][0] + b0)*scale);
        pk[1] = f2bf((acc[mi][ni][1] + b1)*scale);
        pk[2] = f2bf((acc[mi][ni][2] + b2)*scale);
        pk[3] = f2bf((acc[mi][ni][3] + b3)*scale);
        *(bf16x4*)&outb[(long long)row*Nn + col] = pk;
      }
    }
  } else if constexpr (MODE == 4){
    short* outb = (short*)outp + bz*sO;
    float* rowpart = (float*)smem;
    constexpr float LOG2E = 1.4426950408889634f;
    #pragma unroll
    for (int mi = 0; mi < MF; mi++){
      int lrow = wr*128 + mi*16 + lr;
      int row  = m0 + lrow;
      float rs = 0.f;
      #pragma unroll
      for (int ni = 0; ni < NF; ni++){
        int col = n0 + wc*WN + ni*16 + g*4;
        bf16x4 pk;
        #pragma unroll
        for (int i = 0; i < 4; i++){
          float p = exp2f(acc[mi][ni][i]*LOG2E);
          rs += p;
          pk[i] = f2bf(p);
        }
        *(bf16x4*)&outb[(long long)row*Nn + col] = pk;
      }
      rs += __shfl_xor(rs, 16);
      rs += __shfl_xor(rs, 32);
      if (g == 0) rowpart[lrow*2 + wc] = rs;
    }
    __syncthreads();
    {
      float s2 = rowpart[t*2] + rowpart[t*2 + 1];
      partial[((long long)bz*4096 + m0 + t)*16 + by] = s2;
    }
  } else if constexpr (MODE == 5){
    short* outb = (short*)outp + bz*sO;
    const float* dd = dptr + (long long)bz*M;
    #pragma unroll
    for (int mi = 0; mi < MF; mi++){
      int row = m0 + wr*128 + mi*16 + lr;
      float inv = dd[row];
      #pragma unroll
      for (int ni = 0; ni < NF; ni++){
        int col = n0 + wc*WN + ni*16 + g*4;
        bf16x4 pk;
        #pragma unroll
        for (int i = 0; i < 4; i++) pk[i] = f2bf(acc[mi][ni][i]*inv);
        *(bf16x4*)&outb[(long long)row*Nn + col] = pk;
      }
    }
  } else if constexpr (MODE == 1){
    short* outb = (short*)outp + bz*sO;
    #pragma unroll
    for (int ni = 0; ni < NF; ni++){
      int col = n0 + wc*WN + ni*16 + lr;
      float bv2 = bias ? bias[col] : 0.f;
      #pragma unroll
      for (int mi = 0; mi < MF; mi++){
        int row = m0 + wr*128 + mi*16 + g*4;
        bf16x4 pk;
        #pragma unroll
        for (int i = 0; i < 4; i++) pk[i] = f2bf((acc[mi][ni][i] + bv2)*scale);
        *(bf16x4*)&outb[(long long)col*M + row] = pk;
      }
    }
  } else {
    float* outb = (float*)outp + bz*sO;
    const float* rx = resid + bz*sO;
    #pragma unroll
    for (int ni = 0; ni < NF; ni++){
      int col = n0 + wc*WN + ni*16 + lr;
      float bv2 = bias[col];
      #pragma unroll
      for (int mi = 0; mi < MF; mi++){
        int row = m0 + wr*128 + mi*16 + g*4;
        long long off = (long long)col*M + row;
        float4 xr = *(const float4*)&rx[off];
        float4 o;
        o.x = acc[mi][ni][0] + bv2 + xr.x;
        o.y = acc[mi][ni][1] + bv2 + xr.y;
        o.z = acc[mi][ni][2] + bv2 + xr.z;
        o.w = acc[mi][ni][3] + bv2 + xr.w;
        *(float4*)&outb[off] = o;
      }
    }
  }
}

extern "C" void kernel_launch(void* const* d_in, const int* in_sizes, int n_in,
                              void* d_out, int out_size, void* d_ws, size_t ws_size,
                              hipStream_t stream)
{
  const float* x   = (const float*)d_in[0];
  const float* gnw = (const float*)d_in[1];
  const float* gnb = (const float*)d_in[2];
  const float* Wq  = (const float*)d_in[3];
  const float* bq  = (const float*)d_in[4];
  const float* Wk  = (const float*)d_in[5];
  const float* bk  = (const float*)d_in[6];
  const float* Wv  = (const float*)d_in[7];
  const float* bvp = (const float*)d_in[8];
  const float* Wo  = (const float*)d_in[9];
  const float* bo  = (const float*)d_in[10];
  float* out = (float*)d_out;

  char* ws = (char*)d_ws;
  const size_t MB = 1ull << 20;
  short* h      = (short*)(ws);
  short* q      = (short*)(ws + 16*MB);
  short* kmat   = (short*)(ws + 32*MB);
  short* vt     = (short*)(ws + 48*MB);
  short* ao     = (short*)(ws + 64*MB);
  short* wqb    = (short*)(ws + 80*MB);
  short* wkb    = wqb + 262144;
  short* wvb    = wkb + 262144;
  short* wob    = wvb + 262144;
  float* stats  = (float*)(ws + 82*MB);
  float* inv_den= (float*)(ws + 82*MB + 8192);
  float* partial= (float*)(ws + 83*MB);
  short* S      = (short*)(ws + 84*MB);

  const int SH256 = 65536, SH128 = 49152;   // dynamic LDS (<=64KB, no attr needed)

  dim3 blk(256);
  gn_stats<<<dim3(128), blk, 0, stream>>>(x, stats);
  gn_apply<<<dim3(64,4), blk, 0, stream>>>(x, stats, gnw, gnb, h);
  f2bf_all<<<dim3(512), blk, 0, stream>>>(Wq, Wk, Wv, Wo, wqb, wkb, wvb, wob);

  const long long sTok = 4096ll*512;
  const long long sS   = 4096ll*4096;
  const float qscale = 0.044194173824159216f;  // 1/sqrt(512)

  gemmW<0,128,0><<<dim3(16,4,4), blk, SH128, stream>>>(h, wqb, bq,  q,    nullptr, 4096, 512, 512, sTok, 0, sTok, qscale, nullptr, nullptr);
  gemmW<0,128,0><<<dim3(16,4,4), blk, SH128, stream>>>(h, wkb, bk,  kmat, nullptr, 4096, 512, 512, sTok, 0, sTok, 1.f, nullptr, nullptr);
  gemmW<1,128,0><<<dim3(16,4,4), blk, SH128, stream>>>(h, wvb, bvp, vt,   nullptr, 4096, 512, 512, sTok, 0, sTok, 1.f, nullptr, nullptr);

  if (ws_size >= 212*MB){
    gemmW<4,256,1><<<dim3(1024), blk, SH256, stream>>>(q, kmat, nullptr, S, nullptr, 4096, 4096, 512, sTok, sTok, sS, 1.f, nullptr, partial);
    reduce_den<<<dim3(64), blk, 0, stream>>>(partial, inv_den, 16384);
    gemmW<5,128,2><<<dim3(256), blk, SH128, stream>>>(S, vt, nullptr, ao, nullptr, 4096, 512, 4096, sS, sTok, sTok, 1.f, inv_den, nullptr);
  } else {
    for (int b = 0; b < 4; b++){
      gemmW<4,256,0><<<dim3(16,16,1), blk, SH256, stream>>>(q + b*sTok, kmat + b*sTok, nullptr, S, nullptr, 4096, 4096, 512, 0, 0, 0, 1.f, nullptr, partial);
      reduce_den<<<dim3(16), blk, 0, stream>>>(partial, inv_den, 4096);
      gemmW<5,128,0><<<dim3(16,4,1), blk, SH128, stream>>>(S, vt + b*sTok, nullptr, ao + b*sTok, nullptr, 4096, 512, 4096, 0, 0, 0, 1.f, inv_den, nullptr);
    }
  }

  gemmW<2,128,0><<<dim3(16,4,4), blk, SH128, stream>>>(ao, wob, bo, out, x, 4096, 512, 512, sTok, 0, sTok, 1.f, nullptr, nullptr);
}